// Round 2
// baseline (265.651 us; speedup 1.0000x reference)
//
#include <hip/hip_runtime.h>

typedef unsigned int uint32;

#define BB 2
#define NN 10000
#define EE_ 80000
#define NODE_ROWS (BB*NN)      // 20000
#define EDGE_ROWS (BB*EE_)     // 160000
#define NODE_BLOCKS 79         // ceil(20000/256)
#define EDGE_BLOCKS 625        // 160000/256 exact
#define CH_THREADS 512

// ---------------------------------------------------------------------------
// Kernel 1: collapse each 66-layer affine chain into (din+1) x 16 f32 W_eff.
// block 0 = node chain (din=31), block 1 = edge chain (din=7).
// ws layout: [0..512) node W_eff (32x16), [512..640) edge W_eff (8x16).
// ---------------------------------------------------------------------------
__global__ __launch_bounds__(CH_THREADS) void collapse_kernel(
    const float* __restrict__ nWin, const float* __restrict__ nbin,
    const float* __restrict__ nWhid, const float* __restrict__ nbhid,
    const float* __restrict__ nWout, const float* __restrict__ nbout,
    const float* __restrict__ eWin, const float* __restrict__ ebin,
    const float* __restrict__ eWhid, const float* __restrict__ ebhid,
    const float* __restrict__ eWout, const float* __restrict__ ebout,
    float* __restrict__ ws)
{
  const int t = threadIdx.x;
  const bool is_edge = (blockIdx.x != 0);
  const float* Win  = is_edge ? eWin  : nWin;
  const float* bin  = is_edge ? ebin  : nbin;
  const float* Whid = is_edge ? eWhid : nWhid;
  const float* bhid = is_edge ? ebhid : nbhid;
  const float* Wout = is_edge ? eWout : nWout;
  const float* bout = is_edge ? ebout : nbout;
  const int din = is_edge ? 7 : 31;
  float* weff = ws + (is_edge ? 32*16 : 0);

  __shared__ float s_wt[64*68];     // WT[k][r]=Whid[i][r][k] (r<64), col 64 = bhid[i][k]
  __shared__ float s_v[2][64*17];   // V[k][c], stride 17 (pad kills bank conflicts)
  __shared__ float s_b[2][16];

  // init V = Wout (64x16), b = bout
  {
    int idx = t * 2;                 // 1024 elems / 512 thr
    float2 w = *(const float2*)(Wout + idx);
    int k = idx >> 4, c = idx & 15;
    s_v[0][k*17 + c]     = w.x;
    s_v[0][k*17 + c + 1] = w.y;
    if (t < 16) s_b[0][t] = bout[t];
  }
  // stage Whid[63] transposed into s_wt
  {
    int idx = t * 8;                 // 4096 elems / 512 thr
    float4 w0 = *(const float4*)(Whid + 63*4096 + idx);
    float4 w1 = *(const float4*)(Whid + 63*4096 + idx + 4);
    int r = idx >> 6, k0 = idx & 63;
    s_wt[(k0 + 0)*68 + r] = w0.x;
    s_wt[(k0 + 1)*68 + r] = w0.y;
    s_wt[(k0 + 2)*68 + r] = w0.z;
    s_wt[(k0 + 3)*68 + r] = w0.w;
    s_wt[(k0 + 4)*68 + r] = w1.x;
    s_wt[(k0 + 5)*68 + r] = w1.y;
    s_wt[(k0 + 6)*68 + r] = w1.z;
    s_wt[(k0 + 7)*68 + r] = w1.w;
    if (t < 64) s_wt[t*68 + 64] = bhid[63*64 + t];
  }
  __syncthreads();

  const int c  = t & 15;
  const int rg = t >> 4;             // 0..31 → rows rg*2, rg*2+1
  int cur = 0;
  for (int s = 0; s < 64; ++s) {
    // prefetch next step's W tile into registers (hides HBM latency under compute)
    float4 pw0 = make_float4(0,0,0,0), pw1 = make_float4(0,0,0,0);
    float pb = 0.f;
    if (s < 63) {
      const int inext = 62 - s;
      int idx = t * 8;
      pw0 = *(const float4*)(Whid + inext*4096 + idx);
      pw1 = *(const float4*)(Whid + inext*4096 + idx + 4);
      if (t < 64) pb = bhid[inext*64 + t];
    }
    // V' = Whid[i] @ V ; b' = b + bhid[i] @ V
    const float* vin = &s_v[cur][0];
    float acc0 = 0.f, acc1 = 0.f;
    float accb = (rg == 0) ? s_b[cur][c] : 0.f;
    #pragma unroll 8
    for (int k = 0; k < 64; ++k) {
      float v = vin[k*17 + c];
      const float2 wt = *(const float2*)&s_wt[k*68 + rg*2];
      acc0 += wt.x * v;
      acc1 += wt.y * v;
      if (rg == 0) accb += s_wt[k*68 + 64] * v;
    }
    const int nxt = cur ^ 1;
    s_v[nxt][(rg*2)*17 + c]     = acc0;
    s_v[nxt][(rg*2 + 1)*17 + c] = acc1;
    if (rg == 0) s_b[nxt][c] = accb;
    __syncthreads();                  // all reads of s_wt / writes of s_v done
    if (s < 63) {
      int idx = t * 8;
      int r = idx >> 6, k0 = idx & 63;
      s_wt[(k0 + 0)*68 + r] = pw0.x;
      s_wt[(k0 + 1)*68 + r] = pw0.y;
      s_wt[(k0 + 2)*68 + r] = pw0.z;
      s_wt[(k0 + 3)*68 + r] = pw0.w;
      s_wt[(k0 + 4)*68 + r] = pw1.x;
      s_wt[(k0 + 5)*68 + r] = pw1.y;
      s_wt[(k0 + 6)*68 + r] = pw1.z;
      s_wt[(k0 + 7)*68 + r] = pw1.w;
      if (t < 64) s_wt[t*68 + 64] = pb;
    }
    __syncthreads();                  // s_wt ready for next step
    cur = nxt;
  }
  // final V in s_v[cur], final bias carry in s_b[cur] (cur==0 after 64 flips)

  // stage [Win; bin] as rows [r][k], stride 65 (reuse s_wt memory)
  {
    const int total = (din + 1) * 64;
    for (int idx = t; idx < total; idx += CH_THREADS) {
      int r = idx >> 6, k = idx & 63;
      s_wt[r*65 + k] = (r < din) ? Win[r*64 + k] : bin[k];
    }
  }
  __syncthreads();
  // W_eff[r][c] = sum_k [Win;bin][r][k] * V[k][c]  (+ carry on bias row)
  {
    const int total = (din + 1) * 16;
    for (int o = t; o < total; o += CH_THREADS) {
      int r = o >> 4, cc = o & 15;
      float acc = 0.f;
      #pragma unroll 8
      for (int k = 0; k < 64; ++k) acc += s_wt[r*65 + k] * s_v[0][k*17 + cc];
      if (r == din) acc += s_b[0][cc];
      weff[r*16 + cc] = acc;
    }
  }
}

// ---------------------------------------------------------------------------
// Kernel 2: apply collapsed affine maps. Blocks [0,79): node rows; rest: edges.
// ---------------------------------------------------------------------------
template<int NF>
static __device__ __forceinline__ void mlp_apply_store(const float* x, const float* sW,
                                                       float* po)
{
  float a[16];
  #pragma unroll
  for (int q = 0; q < 16; ++q) a[q] = sW[NF*16 + q];   // bias row
  #pragma unroll
  for (int j = 0; j < NF; ++j) {
    const float xv = x[j];
    #pragma unroll
    for (int q = 0; q < 16; ++q) a[q] += xv * sW[j*16 + q];
  }
  float4* d = (float4*)po;
  d[0] = make_float4(a[0],  a[1],  a[2],  a[3]);
  d[1] = make_float4(a[4],  a[5],  a[6],  a[7]);
  d[2] = make_float4(a[8],  a[9],  a[10], a[11]);
  d[3] = make_float4(a[12], a[13], a[14], a[15]);
}

__global__ __launch_bounds__(256) void apply_kernel(
    const float* __restrict__ nodes, const float* __restrict__ globals_,
    const float* __restrict__ edges, const int* __restrict__ senders,
    const int* __restrict__ receivers, const float* __restrict__ ws,
    float* __restrict__ out)
{
  __shared__ float sW[32*16];
  const bool is_node = (blockIdx.x < NODE_BLOCKS);
  {
    const float* src = is_node ? ws : ws + 32*16;
    const int n = is_node ? 32*16 : 8*16;
    for (int j = threadIdx.x; j < n; j += 256) sW[j] = src[j];
  }
  __syncthreads();

  if (is_node) {
    const int rn = blockIdx.x*256 + threadIdx.x;
    if (rn >= NODE_ROWS) return;
    float x[31];
    const float* p = nodes + (size_t)rn*30;
    #pragma unroll
    for (int j = 0; j < 15; ++j) {
      float2 u = *(const float2*)(p + j*2);
      x[2*j]     = u.x;
      x[2*j + 1] = u.y;
    }
    const int b = (rn >= NN) ? 1 : 0;
    x[30] = globals_[b];
    mlp_apply_store<31>(x, sW, out + (size_t)rn*16);
  } else {
    const int re = (blockIdx.x - NODE_BLOCKS)*256 + threadIdx.x;  // < 160000 exact
    const int b = (re >= EE_) ? 1 : 0;
    float x[7];
    const float* ep = edges + (size_t)re*3;
    x[0] = ep[0]; x[1] = ep[1]; x[2] = ep[2];
    const int si = senders[re], ri = receivers[re];
    const float* ps = nodes + ((size_t)(b*NN + si))*30;
    const float* pr = nodes + ((size_t)(b*NN + ri))*30;
    const float dx = ps[0] - pr[0];
    const float dy = ps[1] - pr[1];
    const float dz = ps[2] - pr[2];
    x[3] = dx; x[4] = dy; x[5] = dz;
    x[6] = sqrtf(dx*dx + dy*dy + dz*dz);
    mlp_apply_store<7>(x, sW, out + (size_t)(NODE_ROWS + re)*16);
  }
}

extern "C" void kernel_launch(void* const* d_in, const int* in_sizes, int n_in,
                              void* d_out, int out_size, void* d_ws, size_t ws_size,
                              hipStream_t stream)
{
  const float* nodes    = (const float*)d_in[0];
  const float* globals_ = (const float*)d_in[1];
  const float* edges    = (const float*)d_in[2];
  const int* senders   = (const int*)d_in[3];
  const int* receivers = (const int*)d_in[4];
  const float* nWin  = (const float*)d_in[5];
  const float* nbin  = (const float*)d_in[6];
  const float* nWhid = (const float*)d_in[7];
  const float* nbhid = (const float*)d_in[8];
  const float* nWout = (const float*)d_in[9];
  const float* nbout = (const float*)d_in[10];
  const float* eWin  = (const float*)d_in[11];
  const float* ebin  = (const float*)d_in[12];
  const float* eWhid = (const float*)d_in[13];
  const float* ebhid = (const float*)d_in[14];
  const float* eWout = (const float*)d_in[15];
  const float* ebout = (const float*)d_in[16];
  float* ws = (float*)d_ws;
  float* out = (float*)d_out;

  collapse_kernel<<<dim3(2), dim3(CH_THREADS), 0, stream>>>(
      nWin, nbin, nWhid, nbhid, nWout, nbout,
      eWin, ebin, eWhid, ebhid, eWout, ebout, ws);

  apply_kernel<<<dim3(NODE_BLOCKS + EDGE_BLOCKS), dim3(256), 0, stream>>>(
      nodes, globals_, edges, senders, receivers, ws, out);
}

// Round 3
// 59.118 us; speedup vs baseline: 4.4936x; 4.4936x over previous
//
#include <hip/hip_runtime.h>

#define BB 2
#define NN 10000
#define EE_ 80000
#define NODE_ROWS (BB*NN)      // 20000
#define EDGE_ROWS (BB*EE_)     // 160000
#define NODE_BLOCKS 79         // ceil(20000/256)
#define EDGE_BLOCKS 625        // 160000/256 exact

#define SLOT 4160              // floats per augmented matrix (65 x 64)
#define WS_BUFA 1024
#define WS_BUFB (1024 + 64*SLOT)

// ---------------------------------------------------------------------------
// tree_level: dst[chain*half + j] = src[2j] ∘ src[2j+1]  (augmented compose)
// aug matrix: rows 0..63 = W (row-major 64x64), row 64 = bias.
// raw=1: level 0 reads directly from Whid/bhid arrays.
// ---------------------------------------------------------------------------
__global__ __launch_bounds__(256) void tree_level(
    const float* __restrict__ nW, const float* __restrict__ nb,
    const float* __restrict__ eW, const float* __restrict__ eb,
    const float* __restrict__ src, float* __restrict__ dst,
    int half, int raw)
{
  const int t = threadIdx.x;
  const int chain = blockIdx.x / half;
  const int j = blockIdx.x % half;

  __shared__ float s_at[64*68];   // A^T: [k][r], r<=64 (col 64 = A bias); stride 68
  __shared__ float s_b[65*64];    // B rows 0..63 + bias row 64
  __shared__ float s_bp[4*64];    // bias-row partials

  const float* Wa; const float* ba; const float* Wb; const float* bb;
  if (raw) {
    const float* W = chain ? eW : nW;
    const float* b = chain ? eb : nb;
    Wa = W + (size_t)(2*j)*4096;   ba = b + (2*j)*64;
    Wb = W + (size_t)(2*j+1)*4096; bb = b + (2*j+1)*64;
  } else {
    const float* A  = src + (size_t)(chain*2*half + 2*j)*SLOT;
    const float* Bm = src + (size_t)(chain*2*half + 2*j+1)*SLOT;
    Wa = A; ba = A + 4096; Wb = Bm; bb = Bm + 4096;
  }

  // stage A transposed (coalesced read, scattered b32 write)
  #pragma unroll
  for (int i = 0; i < 17; ++i) {
    int idx = t + i*256;
    if (idx < 4160) {
      int r = idx >> 6, k = idx & 63;
      float v = (r < 64) ? Wa[idx] : ba[k];
      s_at[k*68 + r] = v;
    }
  }
  // stage B linear (float4)
  #pragma unroll
  for (int i = 0; i < 4; ++i) {
    int idx4 = t + i*256;
    *(float4*)&s_b[idx4*4] = *(const float4*)&Wb[idx4*4];
  }
  if (t < 16) *(float4*)&s_b[4096 + t*4] = *(const float4*)&bb[t*4];
  __syncthreads();

  // compute 64x64 part: 4x4 register tiles, all-b128 LDS reads
  const int ti = t >> 4, tj = t & 15;
  float acc[4][4];
  #pragma unroll
  for (int d = 0; d < 4; ++d)
    #pragma unroll
    for (int e = 0; e < 4; ++e) acc[d][e] = 0.f;

  #pragma unroll 4
  for (int k = 0; k < 64; ++k) {
    float4 a4 = *(const float4*)&s_at[k*68 + 4*ti];
    float4 b4 = *(const float4*)&s_b[k*64 + 4*tj];
    float av[4] = {a4.x, a4.y, a4.z, a4.w};
    float bv[4] = {b4.x, b4.y, b4.z, b4.w};
    #pragma unroll
    for (int d = 0; d < 4; ++d)
      #pragma unroll
      for (int e = 0; e < 4; ++e) acc[d][e] += av[d]*bv[e];
  }
  float* D = dst + (size_t)(chain*half + j)*SLOT;
  #pragma unroll
  for (int d = 0; d < 4; ++d)
    *(float4*)&D[(4*ti + d)*64 + 4*tj] =
        make_float4(acc[d][0], acc[d][1], acc[d][2], acc[d][3]);

  // bias row: b_new = bA @ WB + bB  (k-split across 4 waves, LDS reduce)
  {
    int c = t & 63, kq = t >> 6;
    float p = 0.f;
    #pragma unroll 4
    for (int kk = 0; kk < 16; ++kk) {
      int k = kq*16 + kk;
      p += s_at[k*68 + 64] * s_b[k*64 + c];
    }
    s_bp[kq*64 + c] = p;
  }
  __syncthreads();
  if (t < 64)
    D[4096 + t] = s_bp[t] + s_bp[64 + t] + s_bp[128 + t] + s_bp[192 + t] + s_b[4096 + t];
}

// ---------------------------------------------------------------------------
// finalize: W_eff = ([Win;bin] ∘ H) ∘ [Wout;bout]  → (din+1)x16 into ws
// block 0 = node (din=31, ws+0), block 1 = edge (din=7, ws+512)
// ---------------------------------------------------------------------------
__global__ __launch_bounds__(256) void finalize_kernel(
    const float* __restrict__ nWin, const float* __restrict__ nbin,
    const float* __restrict__ nWout, const float* __restrict__ nbout,
    const float* __restrict__ eWin, const float* __restrict__ ebin,
    const float* __restrict__ eWout, const float* __restrict__ ebout,
    const float* __restrict__ src, float* __restrict__ ws)
{
  const int t = threadIdx.x;
  const int chain = blockIdx.x;          // 0 node, 1 edge
  const int din = chain ? 7 : 31;
  const float* Win  = chain ? eWin  : nWin;
  const float* bin  = chain ? ebin  : nbin;
  const float* Wout = chain ? eWout : nWout;
  const float* bout = chain ? ebout : nbout;
  const float* H = src + (size_t)chain*SLOT;
  float* weff = ws + (chain ? 512 : 0);

  __shared__ float s_h[65*64];      // H rows + bias row
  __shared__ float s_aint[64*34];   // Ain^T [k][r], r <= 31
  __shared__ float s_tc[64*34];     // T stored c-major: [c][r]
  __shared__ float s_wo[64*16];
  __shared__ float s_bo[16];

  #pragma unroll
  for (int i = 0; i < 5; ++i) {
    int idx4 = t + i*256;
    if (idx4 < 1040) *(float4*)&s_h[idx4*4] = *(const float4*)&H[idx4*4];
  }
  {
    int nrows = din + 1;
    for (int idx = t; idx < nrows*64; idx += 256) {
      int r = idx >> 6, k = idx & 63;
      float v = (r < din) ? Win[r*64 + k] : bin[k];
      s_aint[k*34 + r] = v;
    }
  }
  if (t < 256) { int idx4 = t; *(float4*)&s_wo[idx4*4] = *(const float4*)&Wout[idx4*4]; }
  if (t < 4)   *(float4*)&s_bo[t*4] = *(const float4*)&bout[t*4];
  __syncthreads();

  // phase A: T = Ain ∘ H  (rows 2ti..2ti+1, cols 4tj..4tj+3) → s_tc c-major
  {
    const int ti = t >> 4, tj = t & 15;
    if (2*ti < din + 1) {
      float accA[2][4];
      #pragma unroll
      for (int d = 0; d < 2; ++d)
        #pragma unroll
        for (int e = 0; e < 4; ++e) accA[d][e] = 0.f;
      #pragma unroll 4
      for (int k = 0; k < 64; ++k) {
        float2 a2 = *(const float2*)&s_aint[k*34 + 2*ti];
        float4 h4 = *(const float4*)&s_h[k*64 + 4*tj];
        float hv[4] = {h4.x, h4.y, h4.z, h4.w};
        #pragma unroll
        for (int e = 0; e < 4; ++e) {
          accA[0][e] += a2.x * hv[e];
          accA[1][e] += a2.y * hv[e];
        }
      }
      #pragma unroll
      for (int d = 0; d < 2; ++d)
        #pragma unroll
        for (int e = 0; e < 4; ++e) {
          float v = accA[d][e];
          if (2*ti + d == din) v += s_h[4096 + 4*tj + e];   // + H bias on row din
          s_tc[(4*tj + e)*34 + 2*ti + d] = v;
        }
    }
  }
  __syncthreads();
  // phase B: weff[r][q] = sum_c Tc[c][r]*Wout[c][q] (+ bout at r==din)
  {
    const int r = t >> 3, qp = t & 7;
    if (r < din + 1) {
      float a0 = 0.f, a1 = 0.f;
      #pragma unroll 4
      for (int c = 0; c < 64; ++c) {
        float tv = s_tc[c*34 + r];
        float2 w2 = *(const float2*)&s_wo[c*16 + 2*qp];
        a0 += tv * w2.x; a1 += tv * w2.y;
      }
      if (r == din) { a0 += s_bo[2*qp]; a1 += s_bo[2*qp + 1]; }
      *(float2*)&weff[r*16 + 2*qp] = make_float2(a0, a1);
    }
  }
}

// ---------------------------------------------------------------------------
// apply (unchanged from R2): blocks [0,79) node rows; rest edge rows.
// ---------------------------------------------------------------------------
template<int NF>
static __device__ __forceinline__ void mlp_apply_store(const float* x, const float* sW,
                                                       float* po)
{
  float a[16];
  #pragma unroll
  for (int q = 0; q < 16; ++q) a[q] = sW[NF*16 + q];   // bias row
  #pragma unroll
  for (int j = 0; j < NF; ++j) {
    const float xv = x[j];
    #pragma unroll
    for (int q = 0; q < 16; ++q) a[q] += xv * sW[j*16 + q];
  }
  float4* d = (float4*)po;
  d[0] = make_float4(a[0],  a[1],  a[2],  a[3]);
  d[1] = make_float4(a[4],  a[5],  a[6],  a[7]);
  d[2] = make_float4(a[8],  a[9],  a[10], a[11]);
  d[3] = make_float4(a[12], a[13], a[14], a[15]);
}

__global__ __launch_bounds__(256) void apply_kernel(
    const float* __restrict__ nodes, const float* __restrict__ globals_,
    const float* __restrict__ edges, const int* __restrict__ senders,
    const int* __restrict__ receivers, const float* __restrict__ ws,
    float* __restrict__ out)
{
  __shared__ float sW[32*16];
  const bool is_node = (blockIdx.x < NODE_BLOCKS);
  {
    const float* src = is_node ? ws : ws + 512;
    const int n = is_node ? 32*16 : 8*16;
    for (int j = threadIdx.x; j < n; j += 256) sW[j] = src[j];
  }
  __syncthreads();

  if (is_node) {
    const int rn = blockIdx.x*256 + threadIdx.x;
    if (rn >= NODE_ROWS) return;
    float x[31];
    const float* p = nodes + (size_t)rn*30;
    #pragma unroll
    for (int j = 0; j < 15; ++j) {
      float2 u = *(const float2*)(p + j*2);
      x[2*j]     = u.x;
      x[2*j + 1] = u.y;
    }
    const int b = (rn >= NN) ? 1 : 0;
    x[30] = globals_[b];
    mlp_apply_store<31>(x, sW, out + (size_t)rn*16);
  } else {
    const int re = (blockIdx.x - NODE_BLOCKS)*256 + threadIdx.x;
    const int b = (re >= EE_) ? 1 : 0;
    float x[7];
    const float* ep = edges + (size_t)re*3;
    x[0] = ep[0]; x[1] = ep[1]; x[2] = ep[2];
    const int si = senders[re], ri = receivers[re];
    const float* ps = nodes + ((size_t)(b*NN + si))*30;
    const float* pr = nodes + ((size_t)(b*NN + ri))*30;
    const float dx = ps[0] - pr[0];
    const float dy = ps[1] - pr[1];
    const float dz = ps[2] - pr[2];
    x[3] = dx; x[4] = dy; x[5] = dz;
    x[6] = sqrtf(dx*dx + dy*dy + dz*dz);
    mlp_apply_store<7>(x, sW, out + (size_t)(NODE_ROWS + re)*16);
  }
}

extern "C" void kernel_launch(void* const* d_in, const int* in_sizes, int n_in,
                              void* d_out, int out_size, void* d_ws, size_t ws_size,
                              hipStream_t stream)
{
  const float* nodes    = (const float*)d_in[0];
  const float* globals_ = (const float*)d_in[1];
  const float* edges    = (const float*)d_in[2];
  const int* senders   = (const int*)d_in[3];
  const int* receivers = (const int*)d_in[4];
  const float* nWin  = (const float*)d_in[5];
  const float* nbin  = (const float*)d_in[6];
  const float* nWhid = (const float*)d_in[7];
  const float* nbhid = (const float*)d_in[8];
  const float* nWout = (const float*)d_in[9];
  const float* nbout = (const float*)d_in[10];
  const float* eWin  = (const float*)d_in[11];
  const float* ebin  = (const float*)d_in[12];
  const float* eWhid = (const float*)d_in[13];
  const float* ebhid = (const float*)d_in[14];
  const float* eWout = (const float*)d_in[15];
  const float* ebout = (const float*)d_in[16];
  float* ws  = (float*)d_ws;
  float* out = (float*)d_out;
  float* bufA = ws + WS_BUFA;
  float* bufB = ws + WS_BUFB;

  // 6-level pairwise tree over the 64 hidden affine layers (per chain)
  tree_level<<<64, 256, 0, stream>>>(nWhid, nbhid, eWhid, ebhid, bufA, bufA, 32, 1);
  tree_level<<<32, 256, 0, stream>>>(nWhid, nbhid, eWhid, ebhid, bufA, bufB, 16, 0);
  tree_level<<<16, 256, 0, stream>>>(nWhid, nbhid, eWhid, ebhid, bufB, bufA,  8, 0);
  tree_level<<< 8, 256, 0, stream>>>(nWhid, nbhid, eWhid, ebhid, bufA, bufB,  4, 0);
  tree_level<<< 4, 256, 0, stream>>>(nWhid, nbhid, eWhid, ebhid, bufB, bufA,  2, 0);
  tree_level<<< 2, 256, 0, stream>>>(nWhid, nbhid, eWhid, ebhid, bufA, bufB,  1, 0);

  finalize_kernel<<<2, 256, 0, stream>>>(nWin, nbin, nWout, nbout,
                                         eWin, ebin, eWout, ebout, bufB, ws);

  apply_kernel<<<NODE_BLOCKS + EDGE_BLOCKS, 256, 0, stream>>>(
      nodes, globals_, edges, senders, receivers, ws, out);
}